// Round 11
// baseline (200.888 us; speedup 1.0000x reference)
//
#include <hip/hip_runtime.h>

#define STEPS 100
#define GCONST 20.0f

typedef float v4f __attribute__((ext_vector_type(4)));

// Build A^t table (t=0..STEPS) by sequential multiplication — bit-identical
// to the round-9 kernel's running product. Runs every call (d_ws is
// re-poisoned before each timed launch).
__global__ void build_pow_table(
    const float* __restrict__ pa1,
    const float* __restrict__ pa2,
    const float* __restrict__ pth,
    float* __restrict__ tbl)
{
    if (threadIdx.x == 0 && blockIdx.x == 0) {
        const float a1 = *pa1, a2 = *pa2, th = *pth;
        const float denom = 1.0f - a1 * (1.0f - th);
        const float w = (1.0f - a1) * (1.0f - th);
        const float A = (1.0f - a2) + w * a2 / denom;
        float p = 1.0f;
        for (int t = 0; t <= STEPS; ++t) { tbl[t] = p; p *= A; }
    }
}

// Fill-shaped closed-form writer: flat float4 index g -> out4[g], one pure
// linear grid-stride store stream (byte-identical address pattern to the
// harness's fillBufferAligned, which sustains 6.6 TB/s). Values:
//   y[t][i] = ys + (k*A^t)    * (h0[i]-hs)     (g in first half)
//   h[t][i] = hs + A^(t+1)    * (h0[i]-hs)     (g in second half)
// h0 (1 MB) is L2/L3-resident after first touch; reads are noise vs 200 MB
// of writes.
__global__ __launch_bounds__(256) void sim_fill_kernel(
    const float* __restrict__ h0,
    const float* __restrict__ pa1,
    const float* __restrict__ pa2,
    const float* __restrict__ pth,
    const float* __restrict__ tbl,
    float* __restrict__ out,
    int n)
{
    const unsigned nv = (unsigned)n >> 2;      // float4 groups per time-row
    const unsigned half = (unsigned)STEPS * nv; // float4 groups in y region
    const unsigned total = 2u * half;

    const float a1 = *pa1, a2 = *pa2, th = *pth;
    const float denom = 1.0f - a1 * (1.0f - th);
    const float w  = (1.0f - a1) * (1.0f - th);
    const float A  = (1.0f - a2) + w * a2 / denom;
    const float B  = w * GCONST / denom;
    const float hs = B / (1.0f - A);
    const float ys = (GCONST + a2 * hs) / denom;
    const float k  = a2 / denom;

    const v4f* __restrict__ h0v = reinterpret_cast<const v4f*>(h0);
    v4f* __restrict__ out4 = reinterpret_cast<v4f*>(out);

    const unsigned stride = gridDim.x * blockDim.x;
    for (unsigned g = blockIdx.x * blockDim.x + threadIdx.x; g < total; g += stride) {
        unsigned gr = g;
        const bool isH = g >= half;
        if (isH) gr -= half;
        const unsigned t  = gr / nv;
        const unsigned i4 = gr - t * nv;

        // tbl[t+1] is exactly fl(tbl[t]*A) — same product chain as the
        // sequential recurrence.
        const float c1 = isH ? tbl[t + 1] : k * tbl[t];
        const float c0 = isH ? hs : ys;

        const v4f hv = h0v[i4];
        v4f val;
        val.x = c0 + c1 * (hv.x - hs);
        val.y = c0 + c1 * (hv.y - hs);
        val.z = c0 + c1 * (hv.z - hs);
        val.w = c0 + c1 * (hv.w - hs);

        out4[g] = val;
    }
}

// Generic scalar fallback (any n), round-9 style closed form.
__global__ void sim_scan_generic_kernel(
    const float* __restrict__ h0,
    const float* __restrict__ pa1,
    const float* __restrict__ pa2,
    const float* __restrict__ pth,
    float* __restrict__ out,
    int n)
{
    int i = blockIdx.x * blockDim.x + threadIdx.x;
    if (i >= n) return;

    const float a1 = *pa1, a2 = *pa2, th = *pth;
    const float denom = 1.0f - a1 * (1.0f - th);
    const float w  = (1.0f - a1) * (1.0f - th);
    const float A  = (1.0f - a2) + w * a2 / denom;
    const float B  = w * GCONST / denom;
    const float hs = B / (1.0f - A);
    const float ys = (GCONST + a2 * hs) / denom;
    const float k  = a2 / denom;

    float d = h0[i] - hs;
    float* oy = out + i;
    float* oh = out + (size_t)STEPS * (size_t)n + i;

    for (int t = 0; t < STEPS; ++t) {
        float y = ys + k * d;
        d *= A;
        float h = hs + d;
        *oy = y;
        *oh = h;
        oy += n;
        oh += n;
    }
}

extern "C" void kernel_launch(void* const* d_in, const int* in_sizes, int n_in,
                              void* d_out, int out_size, void* d_ws, size_t ws_size,
                              hipStream_t stream) {
    const float* h0 = (const float*)d_in[0];
    const float* a1 = (const float*)d_in[1];
    const float* a2 = (const float*)d_in[2];
    const float* th = (const float*)d_in[3];
    float* out = (float*)d_out;
    float* tbl = (float*)d_ws;  // 101 floats

    const int n = in_sizes[0];

    if ((n & 3) == 0 && n > 0) {
        build_pow_table<<<1, 64, 0, stream>>>(a1, a2, th, tbl);
        const unsigned total = (unsigned)(n / 4) * 2u * STEPS;
        const int block = 256;
        unsigned blocks = (total + block - 1) / block;
        if (blocks > 2048u) blocks = 2048u;
        sim_fill_kernel<<<blocks, block, 0, stream>>>(h0, a1, a2, th, tbl, out, n);
    } else if (n > 0) {
        sim_scan_generic_kernel<<<(n + 255) / 256, 256, 0, stream>>>(
            h0, a1, a2, th, out, n);
    }
}